// Round 1
// baseline (295.803 us; speedup 1.0000x reference)
//
#include <hip/hip_runtime.h>
#include <hip/hip_bf16.h>

typedef __attribute__((ext_vector_type(8))) short bf16x8;
typedef __attribute__((ext_vector_type(4))) float f32x4;

// Kinematic tree ancestor tables (full ancestor paths, from reference)
static constexpr int ALEN[24] = {0,1,1,1,2,2,2,3,3,3,4,4,4,4,4,5,5,5,6,6,7,7,8,8};
static constexpr int AOFF[24] = {0,0,1,2,3,5,7,9,12,15,18,22,26,30,34,38,43,48,53,59,65,72,79,87};
static constexpr int AFLAT[95] = {
  0, 0, 0,
  0,1, 0,2, 0,3,
  0,1,4, 0,2,5, 0,3,6,
  0,1,4,7, 0,2,5,8, 0,3,6,9, 0,3,6,9, 0,3,6,9,
  0,3,6,9,12, 0,3,6,9,13, 0,3,6,9,14,
  0,3,6,9,13,16, 0,3,6,9,14,17,
  0,3,6,9,13,16,18, 0,3,6,9,14,17,19,
  0,3,6,9,13,16,18,20, 0,3,6,9,14,17,19,21};

static __device__ __forceinline__ unsigned short f2bf(float f) {
  unsigned int u = __float_as_uint(f);
  u = (u + 0x7fffu + ((u >> 16) & 1u)) >> 16;   // RTNE
  return (unsigned short)u;
}

// ---------------------------------------------------------------------------
// K1a: G[147][401] = [ktd_head(144x1024); deccam_w[:, :1024](3x1024)] @ [fc2_w | fc2_b]
// ---------------------------------------------------------------------------
__global__ __launch_bounds__(64) void combineG(const float* __restrict__ ktd,
                                               const float* __restrict__ dcw,
                                               const float* __restrict__ w2,
                                               const float* __restrict__ b2,
                                               float* __restrict__ G) {
  int c = blockIdx.x * 64 + threadIdx.x;
  if (c > 400) return;
  int o0 = blockIdx.y * 4;
  const float* vp[4];
  #pragma unroll
  for (int oi = 0; oi < 4; oi++) {
    int o = o0 + oi; if (o > 146) o = 146;
    vp[oi] = (o < 144) ? (ktd + (size_t)o * 1078) : (dcw + (size_t)(o - 144) * 2051);
  }
  float acc[4] = {0.f, 0.f, 0.f, 0.f};
  #pragma unroll 8
  for (int h = 0; h < 1024; h++) {
    float wv = (c < 400) ? w2[h * 400 + c] : b2[h];
    #pragma unroll
    for (int oi = 0; oi < 4; oi++) acc[oi] += vp[oi][h] * wv;
  }
  #pragma unroll
  for (int oi = 0; oi < 4; oi++) {
    int o = o0 + oi;
    if (o < 147) G[o * 401 + c] = acc[oi];
  }
}

// ---------------------------------------------------------------------------
// K1b: H[13][267] = [decshape_w(10x1024); deccam_w[:,1024:2048](3x1024)] @ [fc1_w | fc1_b]
// ---------------------------------------------------------------------------
__global__ __launch_bounds__(64) void combineH(const float* __restrict__ dsw,
                                               const float* __restrict__ dcw,
                                               const float* __restrict__ w1,
                                               const float* __restrict__ b1,
                                               float* __restrict__ H) {
  int c = blockIdx.x * 64 + threadIdx.x;
  if (c > 266) return;
  int o0 = blockIdx.y * 4;
  const float* vp[4];
  #pragma unroll
  for (int oi = 0; oi < 4; oi++) {
    int o = o0 + oi; if (o > 12) o = 12;
    vp[oi] = (o < 10) ? (dsw + (size_t)o * 1024) : (dcw + (size_t)(o - 10) * 2051 + 1024);
  }
  float acc[4] = {0.f, 0.f, 0.f, 0.f};
  #pragma unroll 8
  for (int h = 0; h < 1024; h++) {
    float wv = (c < 266) ? w1[h * 266 + c] : b1[h];
    #pragma unroll
    for (int oi = 0; oi < 4; oi++) acc[oi] += vp[oi][h] * wv;
  }
  #pragma unroll
  for (int oi = 0; oi < 4; oi++) {
    int o = o0 + oi;
    if (o < 13) H[o * 267 + c] = acc[oi];
  }
}

// ---------------------------------------------------------------------------
// K2: assemble Mb[160][424] (bf16, row-major over outputs o = "B^T" layout) + bias Cb[160]
// z layout: [0:256)=x  [256:400)=init_pose  [400:410)=init_shape  [410:413)=init_cam
// out layout: o in [0:3)=cam  [3:147)=pose(base, no +init_pose)  [147:157)=shape
// ---------------------------------------------------------------------------
__global__ __launch_bounds__(256) void assembleM(const float* __restrict__ G,
                                                 const float* __restrict__ H,
                                                 const float* __restrict__ dcw,
                                                 const float* __restrict__ dcb,
                                                 const float* __restrict__ dsb,
                                                 const float* __restrict__ ktd,
                                                 const float* __restrict__ ktdb,
                                                 unsigned short* __restrict__ Mb,
                                                 float* __restrict__ Cb) {
  int o = blockIdx.x;
  for (int c = threadIdx.x; c < 424; c += 256) {
    float val = 0.f;
    if (c < 413) {
      if (o < 3) {
        if (c < 400) val += G[(144 + o) * 401 + c];
        if (c < 256) val += H[(10 + o) * 267 + c];
        if (c >= 400 && c < 410) val += H[(10 + o) * 267 + 256 + (c - 400)];
        if (c >= 410) {
          val += dcw[(size_t)o * 2051 + 2048 + (c - 410)];
          if ((c - 410) == o) val += 1.f;
        }
      } else if (o < 147) {
        int t = o - 3, j = t / 6;
        if (c < 400) val = G[t * 401 + c];
        int cj = c - 256 - j;            // init_pose[..., j:j+6] quirk slice
        if (cj >= 0 && cj < 6) val += ktd[(size_t)t * 1078 + 1024 + 6 * ALEN[j] + cj];
      } else if (o < 157) {
        int s = o - 147;
        if (c < 256) val = H[s * 267 + c];
        if (c >= 400 && c < 410) {
          val += H[s * 267 + 256 + (c - 400)];
          if ((c - 400) == s) val += 1.f;
        }
      }
    }
    Mb[o * 424 + c] = f2bf(val);
  }
  if (threadIdx.x == 0 && o < 157) {
    float bv;
    if (o < 3)        bv = G[(144 + o) * 401 + 400] + H[(10 + o) * 267 + 266] + dcb[o];
    else if (o < 147) bv = G[(o - 3) * 401 + 400] + ktdb[o - 3];
    else              bv = H[(o - 147) * 267 + 266] + dsb[o - 147];
    Cb[o] = bv;
  }
}

// ---------------------------------------------------------------------------
// K3: main GEMM  C[rows x 160] = Z[rows x 416] @ Mb^T   (MFMA 16x16x32 bf16)
//   64 rows/block, 4 waves, wave w handles rows [16w,16w+16); full N=160 per wave
// ---------------------------------------------------------------------------
__global__ __launch_bounds__(256) void main_gemm(const float* __restrict__ x,
                                                 const float* __restrict__ ipose,
                                                 const float* __restrict__ ishape,
                                                 const float* __restrict__ icam,
                                                 const unsigned short* __restrict__ Mb,
                                                 const float* __restrict__ Cb,
                                                 float* __restrict__ out,
                                                 float* __restrict__ pb,
                                                 int rows) {
  __shared__ unsigned short zt[64 * 424];      // 54.3 KB, bf16 Z tile
  const int rowbase = blockIdx.x * 64;
  const int tid = threadIdx.x;

  // stage x (64 rows x 256)
  const float4* x4 = (const float4*)(x + (size_t)rowbase * 256);
  for (int i = tid; i < 64 * 64; i += 256) {
    int r = i >> 6, c4 = i & 63;
    float4 v = x4[r * 64 + c4];
    ushort4 b; b.x = f2bf(v.x); b.y = f2bf(v.y); b.z = f2bf(v.z); b.w = f2bf(v.w);
    *(ushort4*)&zt[r * 424 + c4 * 4] = b;
  }
  // stage init_pose (64 rows x 144) at col 256
  const float4* p4 = (const float4*)(ipose + (size_t)rowbase * 144);
  for (int i = tid; i < 64 * 36; i += 256) {
    int r = i / 36, c4 = i % 36;
    float4 v = p4[r * 36 + c4];
    ushort4 b; b.x = f2bf(v.x); b.y = f2bf(v.y); b.z = f2bf(v.z); b.w = f2bf(v.w);
    *(ushort4*)&zt[r * 424 + 256 + c4 * 4] = b;
  }
  // init_shape (10) at col 400, init_cam (3) at col 410, zeros 413..423
  for (int i = tid; i < 64 * 10; i += 256) {
    int r = i / 10, cc = i % 10;
    zt[r * 424 + 400 + cc] = f2bf(ishape[(size_t)(rowbase + r) * 10 + cc]);
  }
  for (int i = tid; i < 64 * 3; i += 256) {
    int r = i / 3, cc = i % 3;
    zt[r * 424 + 410 + cc] = f2bf(icam[(size_t)(rowbase + r) * 3 + cc]);
  }
  for (int i = tid; i < 64 * 11; i += 256) {
    int r = i / 11, cc = i % 11;
    zt[r * 424 + 413 + cc] = 0;
  }
  __syncthreads();

  const int wv = tid >> 6, lane = tid & 63;
  const int m = lane & 15, g = lane >> 4;
  const int r0 = wv * 16;

  f32x4 acc[10];
  #pragma unroll
  for (int n = 0; n < 10; n++) acc[n] = (f32x4){0.f, 0.f, 0.f, 0.f};

  for (int k = 0; k < 13; k++) {
    bf16x8 a = *(const bf16x8*)&zt[(r0 + m) * 424 + k * 32 + g * 8];
    #pragma unroll
    for (int n = 0; n < 10; n++) {
      bf16x8 b = *(const bf16x8*)&Mb[(size_t)(n * 16 + m) * 424 + k * 32 + g * 8];
      acc[n] = __builtin_amdgcn_mfma_f32_16x16x32_bf16(a, b, acc[n], 0, 0, 0);
    }
  }

  // epilogue: C/D layout col=lane&15, row=(lane>>4)*4+reg  [m89-verified]
  #pragma unroll
  for (int n = 0; n < 10; n++) {
    int col = n * 16 + m;
    if (col >= 157) continue;
    float bias = Cb[col];
    #pragma unroll
    for (int q = 0; q < 4; q++) {
      int row = rowbase + r0 + g * 4 + q;
      float v = acc[n][q] + bias;
      if (pb != nullptr && col >= 3 && col < 147)
        pb[(size_t)row * 144 + (col - 3)] = v;       // packed pose base
      else
        out[(size_t)row * 157 + col] = v;
    }
  }
}

// ---------------------------------------------------------------------------
// K4: per-row sequential KTD fixup: pose_j = base_j + sum_a W_{j,a} * pose_anc
//     then out_pose = pose + init_pose. Fully unrolled -> p[] stays in VGPRs.
// ---------------------------------------------------------------------------
__global__ __launch_bounds__(64) void fixup(const float* __restrict__ kw,
                                            const float* __restrict__ ipose,
                                            const float* __restrict__ pbase,
                                            int pstride, int poff,
                                            float* __restrict__ out,
                                            int rows) {
  int row = blockIdx.x * 64 + threadIdx.x;
  if (row >= rows) return;
  const float* bp = pbase + (size_t)row * pstride + poff;
  float p[144];
  #pragma unroll
  for (int j = 0; j < 24; j++) {
    float v[6];
    #pragma unroll
    for (int r = 0; r < 6; r++) v[r] = bp[6 * j + r];
    #pragma unroll
    for (int a = 0; a < 8; a++) {
      if (a < ALEN[j]) {
        int anc = AFLAT[AOFF[j] + a];
        #pragma unroll
        for (int r = 0; r < 6; r++) {
          const float* w = kw + (size_t)(6 * j + r) * 1078 + 1024 + 6 * a;
          v[r] += w[0] * p[anc * 6 + 0] + w[1] * p[anc * 6 + 1] + w[2] * p[anc * 6 + 2]
                + w[3] * p[anc * 6 + 3] + w[4] * p[anc * 6 + 4] + w[5] * p[anc * 6 + 5];
        }
      }
    }
    #pragma unroll
    for (int r = 0; r < 6; r++) p[6 * j + r] = v[r];
  }
  const float* iprow = ipose + (size_t)row * 144;
  float* orow = out + (size_t)row * 157 + 3;
  #pragma unroll
  for (int t = 0; t < 144; t++) orow[t] = p[t] + iprow[t];
}

// ---------------------------------------------------------------------------
extern "C" void kernel_launch(void* const* d_in, const int* in_sizes, int n_in,
                              void* d_out, int out_size, void* d_ws, size_t ws_size,
                              hipStream_t stream) {
  const float* x      = (const float*)d_in[0];
  const float* ipose  = (const float*)d_in[1];
  const float* ishape = (const float*)d_in[2];
  const float* icam   = (const float*)d_in[3];
  const float* fc1w   = (const float*)d_in[4];
  const float* fc1b   = (const float*)d_in[5];
  const float* fc2w   = (const float*)d_in[6];
  const float* fc2b   = (const float*)d_in[7];
  const float* dsw    = (const float*)d_in[8];
  const float* dsb    = (const float*)d_in[9];
  const float* dcw    = (const float*)d_in[10];
  const float* dcb    = (const float*)d_in[11];
  const float* ktd    = (const float*)d_in[12];
  const float* ktdb   = (const float*)d_in[13];
  int rows = in_sizes[0] / 256;
  float* ws = (float*)d_ws;

  float* G  = ws;                                   // 147*401 = 58947 f
  float* H  = ws + 59200;                           // 13*267  = 3471 f
  float* Cb = ws + 62720;                           // 160 f
  unsigned short* Mb = (unsigned short*)(ws + 63488); // 160*424 bf16 (byte 253952, 16-aligned)
  float* pb = nullptr;
  size_t need = (size_t)98304 * 4 + (size_t)rows * 144 * 4;
  if (ws_size >= need) pb = ws + 98304;             // packed pose-base [rows][144]

  combineG<<<dim3(7, 37), 64, 0, stream>>>(ktd, dcw, fc2w, fc2b, G);
  combineH<<<dim3(5, 4), 64, 0, stream>>>(dsw, dcw, fc1w, fc1b, H);
  assembleM<<<160, 256, 0, stream>>>(G, H, dcw, dcb, dsb, ktd, ktdb, Mb, Cb);
  main_gemm<<<rows / 64, 256, 0, stream>>>(x, ipose, ishape, icam, Mb, Cb,
                                           (float*)d_out, pb, rows);
  fixup<<<rows / 64, 64, 0, stream>>>(ktd, ipose,
                                      pb ? pb : (float*)d_out,
                                      pb ? 144 : 157, pb ? 0 : 3,
                                      (float*)d_out, rows);
}

// Round 2
// 121.616 us; speedup vs baseline: 2.4323x; 2.4323x over previous
//
#include <hip/hip_runtime.h>
#include <hip/hip_bf16.h>

typedef __attribute__((ext_vector_type(8))) short bf16x8;
typedef __attribute__((ext_vector_type(4))) float f32x4;

// Kinematic tree ancestor tables (full ancestor paths, from reference)
static constexpr int ALEN[24] = {0,1,1,1,2,2,2,3,3,3,4,4,4,4,4,5,5,5,6,6,7,7,8,8};
static constexpr int AOFF[24] = {0,0,1,2,3,5,7,9,12,15,18,22,26,30,34,38,43,48,53,59,65,72,79,87};
static constexpr int AFLAT[95] = {
  0, 0, 0,
  0,1, 0,2, 0,3,
  0,1,4, 0,2,5, 0,3,6,
  0,1,4,7, 0,2,5,8, 0,3,6,9, 0,3,6,9, 0,3,6,9,
  0,3,6,9,12, 0,3,6,9,13, 0,3,6,9,14,
  0,3,6,9,13,16, 0,3,6,9,14,17,
  0,3,6,9,13,16,18, 0,3,6,9,14,17,19,
  0,3,6,9,13,16,18,20, 0,3,6,9,14,17,19,21};

static __device__ __forceinline__ unsigned short f2bf(float f) {
  unsigned int u = __float_as_uint(f);
  u = (u + 0x7fffu + ((u >> 16) & 1u)) >> 16;   // RTNE
  return (unsigned short)u;
}

// ---------------------------------------------------------------------------
// K1: fused combine with 2-level K-split.
//   G[147][401] = [ktd_head(144x1024); deccam_w[:, :1024](3x1024)] @ [fc2_w | fc2_b]
//   H[13][267]  = [decshape_w(10x1024); deccam_w[:,1024:2048](3x1024)] @ [fc1_w | fc1_b]
// blockIdx.y < 37 -> G o-tiles; y in [37,41) -> H o-tiles.
// blockIdx.z = h-chunk (256 h's); within block, 4 waves split it 64 h's each,
// LDS-reduced. Partials Gp[4][147*401] / Hp[4][13*267] summed in assembleM.
// ---------------------------------------------------------------------------
__global__ __launch_bounds__(256) void combine_part(const float* __restrict__ ktd,
                                                    const float* __restrict__ dcw,
                                                    const float* __restrict__ dsw,
                                                    const float* __restrict__ w2,
                                                    const float* __restrict__ b2,
                                                    const float* __restrict__ w1,
                                                    const float* __restrict__ b1,
                                                    float* __restrict__ Gp,
                                                    float* __restrict__ Hp) {
  const bool isH = blockIdx.y >= 37;
  if (isH && blockIdx.x >= 5) return;              // H: c < 320 only (uniform exit)
  const int w = threadIdx.x >> 6, lane = threadIdx.x & 63;
  const int c = blockIdx.x * 64 + lane;
  const int h0 = blockIdx.z * 256 + w * 64;
  __shared__ float red[4][4][64];

  const float* vp[4];
  int o0;
  if (!isH) {
    o0 = blockIdx.y * 4;
    #pragma unroll
    for (int oi = 0; oi < 4; oi++) {
      int o = o0 + oi; if (o > 146) o = 146;
      vp[oi] = (o < 144) ? (ktd + (size_t)o * 1078) : (dcw + (size_t)(o - 144) * 2051);
    }
  } else {
    o0 = (blockIdx.y - 37) * 4;
    #pragma unroll
    for (int oi = 0; oi < 4; oi++) {
      int o = o0 + oi; if (o > 12) o = 12;
      vp[oi] = (o < 10) ? (dsw + (size_t)o * 1024) : (dcw + (size_t)(o - 10) * 2051 + 1024);
    }
  }

  float acc[4] = {0.f, 0.f, 0.f, 0.f};
  if (!isH) {
    #pragma unroll 16
    for (int hh = 0; hh < 64; hh++) {
      int h = h0 + hh;
      float wv = (c < 400) ? w2[h * 400 + c] : ((c == 400) ? b2[h] : 0.f);
      #pragma unroll
      for (int oi = 0; oi < 4; oi++) acc[oi] += vp[oi][h] * wv;
    }
  } else {
    #pragma unroll 16
    for (int hh = 0; hh < 64; hh++) {
      int h = h0 + hh;
      float wv = (c < 266) ? w1[h * 266 + c] : ((c == 266) ? b1[h] : 0.f);
      #pragma unroll
      for (int oi = 0; oi < 4; oi++) acc[oi] += vp[oi][h] * wv;
    }
  }

  #pragma unroll
  for (int oi = 0; oi < 4; oi++) red[w][oi][lane] = acc[oi];
  __syncthreads();
  if (w == 0) {
    #pragma unroll
    for (int oi = 0; oi < 4; oi++) {
      int o = o0 + oi;
      float s = red[0][oi][lane] + red[1][oi][lane] + red[2][oi][lane] + red[3][oi][lane];
      if (!isH) {
        if (o < 147 && c <= 400) Gp[(size_t)blockIdx.z * 59200 + o * 401 + c] = s;
      } else {
        if (o < 13 && c <= 266) Hp[(size_t)blockIdx.z * 3520 + o * 267 + c] = s;
      }
    }
  }
}

// ---------------------------------------------------------------------------
// K2: assemble Mb[160][424] (bf16, "B^T" layout) + bias Cb[160], summing the
// 4 K-chunk partials.
// z layout: [0:256)=x  [256:400)=init_pose  [400:410)=init_shape  [410:413)=init_cam
// out layout: o in [0:3)=cam  [3:147)=pose(base)  [147:157)=shape
// ---------------------------------------------------------------------------
#define GSUM(t, c) (Gp[(t)*401+(c)] + Gp[59200+(t)*401+(c)] + Gp[118400+(t)*401+(c)] + Gp[177600+(t)*401+(c)])
#define HSUM(s, c) (Hp[(s)*267+(c)] + Hp[3520+(s)*267+(c)] + Hp[7040+(s)*267+(c)] + Hp[10560+(s)*267+(c)])

__global__ __launch_bounds__(256) void assembleM(const float* __restrict__ Gp,
                                                 const float* __restrict__ Hp,
                                                 const float* __restrict__ dcw,
                                                 const float* __restrict__ dcb,
                                                 const float* __restrict__ dsb,
                                                 const float* __restrict__ ktd,
                                                 const float* __restrict__ ktdb,
                                                 unsigned short* __restrict__ Mb,
                                                 float* __restrict__ Cb) {
  int o = blockIdx.x;
  for (int c = threadIdx.x; c < 424; c += 256) {
    float val = 0.f;
    if (c < 413) {
      if (o < 3) {
        if (c < 400) val += GSUM(144 + o, c);
        if (c < 256) val += HSUM(10 + o, c);
        if (c >= 400 && c < 410) val += HSUM(10 + o, 256 + (c - 400));
        if (c >= 410) {
          val += dcw[(size_t)o * 2051 + 2048 + (c - 410)];
          if ((c - 410) == o) val += 1.f;
        }
      } else if (o < 147) {
        int t = o - 3, j = t / 6;
        if (c < 400) val = GSUM(t, c);
        int cj = c - 256 - j;            // init_pose[..., j:j+6] quirk slice
        if (cj >= 0 && cj < 6) val += ktd[(size_t)t * 1078 + 1024 + 6 * ALEN[j] + cj];
      } else if (o < 157) {
        int s = o - 147;
        if (c < 256) val = HSUM(s, c);
        if (c >= 400 && c < 410) {
          val += HSUM(s, 256 + (c - 400));
          if ((c - 400) == s) val += 1.f;
        }
      }
    }
    Mb[o * 424 + c] = f2bf(val);
  }
  if (threadIdx.x == 0 && o < 157) {
    float bv;
    if (o < 3)        bv = GSUM(144 + o, 400) + HSUM(10 + o, 266) + dcb[o];
    else if (o < 147) bv = GSUM(o - 3, 400) + ktdb[o - 3];
    else              bv = HSUM(o - 147, 266) + dsb[o - 147];
    Cb[o] = bv;
  }
}

// ---------------------------------------------------------------------------
// K3: main GEMM  C[rows x 160] = Z[rows x 416] @ Mb^T   (MFMA 16x16x32 bf16)
//   64 rows/block, 4 waves, wave w handles rows [16w,16w+16); full N=160 per wave
// ---------------------------------------------------------------------------
__global__ __launch_bounds__(256) void main_gemm(const float* __restrict__ x,
                                                 const float* __restrict__ ipose,
                                                 const float* __restrict__ ishape,
                                                 const float* __restrict__ icam,
                                                 const unsigned short* __restrict__ Mb,
                                                 const float* __restrict__ Cb,
                                                 float* __restrict__ out,
                                                 float* __restrict__ pb,
                                                 int rows) {
  __shared__ unsigned short zt[64 * 424];      // 54.3 KB, bf16 Z tile
  const int rowbase = blockIdx.x * 64;
  const int tid = threadIdx.x;

  // stage x (64 rows x 256)
  const float4* x4 = (const float4*)(x + (size_t)rowbase * 256);
  for (int i = tid; i < 64 * 64; i += 256) {
    int r = i >> 6, c4 = i & 63;
    float4 v = x4[r * 64 + c4];
    ushort4 b; b.x = f2bf(v.x); b.y = f2bf(v.y); b.z = f2bf(v.z); b.w = f2bf(v.w);
    *(ushort4*)&zt[r * 424 + c4 * 4] = b;
  }
  // stage init_pose (64 rows x 144) at col 256
  const float4* p4 = (const float4*)(ipose + (size_t)rowbase * 144);
  for (int i = tid; i < 64 * 36; i += 256) {
    int r = i / 36, c4 = i % 36;
    float4 v = p4[r * 36 + c4];
    ushort4 b; b.x = f2bf(v.x); b.y = f2bf(v.y); b.z = f2bf(v.z); b.w = f2bf(v.w);
    *(ushort4*)&zt[r * 424 + 256 + c4 * 4] = b;
  }
  // init_shape (10) at col 400, init_cam (3) at col 410, zeros 413..423
  for (int i = tid; i < 64 * 10; i += 256) {
    int r = i / 10, cc = i % 10;
    zt[r * 424 + 400 + cc] = f2bf(ishape[(size_t)(rowbase + r) * 10 + cc]);
  }
  for (int i = tid; i < 64 * 3; i += 256) {
    int r = i / 3, cc = i % 3;
    zt[r * 424 + 410 + cc] = f2bf(icam[(size_t)(rowbase + r) * 3 + cc]);
  }
  for (int i = tid; i < 64 * 11; i += 256) {
    int r = i / 11, cc = i % 11;
    zt[r * 424 + 413 + cc] = 0;
  }
  __syncthreads();

  const int wv = tid >> 6, lane = tid & 63;
  const int m = lane & 15, g = lane >> 4;
  const int r0 = wv * 16;

  f32x4 acc[10];
  #pragma unroll
  for (int n = 0; n < 10; n++) acc[n] = (f32x4){0.f, 0.f, 0.f, 0.f};

  for (int k = 0; k < 13; k++) {
    bf16x8 a = *(const bf16x8*)&zt[(r0 + m) * 424 + k * 32 + g * 8];
    #pragma unroll
    for (int n = 0; n < 10; n++) {
      bf16x8 b = *(const bf16x8*)&Mb[(size_t)(n * 16 + m) * 424 + k * 32 + g * 8];
      acc[n] = __builtin_amdgcn_mfma_f32_16x16x32_bf16(a, b, acc[n], 0, 0, 0);
    }
  }

  // epilogue: C/D layout col=lane&15, row=(lane>>4)*4+reg  [m89-verified]
  #pragma unroll
  for (int n = 0; n < 10; n++) {
    int col = n * 16 + m;
    if (col >= 157) continue;
    float bias = Cb[col];
    #pragma unroll
    for (int q = 0; q < 4; q++) {
      int row = rowbase + r0 + g * 4 + q;
      float v = acc[n][q] + bias;
      if (pb != nullptr && col >= 3 && col < 147)
        pb[(size_t)row * 144 + (col - 3)] = v;       // packed pose base
      else
        out[(size_t)row * 157 + col] = v;
    }
  }
}

// ---------------------------------------------------------------------------
// K4: per-row sequential KTD fixup: pose_j = base_j + sum_a W_{j,a} * pose_anc
//     then out_pose = pose + init_pose. Fully unrolled -> p[] stays in VGPRs.
// ---------------------------------------------------------------------------
__global__ __launch_bounds__(256) void fixup(const float* __restrict__ kw,
                                             const float* __restrict__ ipose,
                                             const float* __restrict__ pbase,
                                             int pstride, int poff,
                                             float* __restrict__ out,
                                             int rows) {
  int row = blockIdx.x * 256 + threadIdx.x;
  if (row >= rows) return;
  const float* bp = pbase + (size_t)row * pstride + poff;
  float p[144];
  #pragma unroll
  for (int j = 0; j < 24; j++) {
    float v[6];
    #pragma unroll
    for (int r = 0; r < 6; r++) v[r] = bp[6 * j + r];
    #pragma unroll
    for (int a = 0; a < 8; a++) {
      if (a < ALEN[j]) {
        int anc = AFLAT[AOFF[j] + a];
        #pragma unroll
        for (int r = 0; r < 6; r++) {
          const float* w = kw + (size_t)(6 * j + r) * 1078 + 1024 + 6 * a;
          v[r] += w[0] * p[anc * 6 + 0] + w[1] * p[anc * 6 + 1] + w[2] * p[anc * 6 + 2]
                + w[3] * p[anc * 6 + 3] + w[4] * p[anc * 6 + 4] + w[5] * p[anc * 6 + 5];
        }
      }
    }
    #pragma unroll
    for (int r = 0; r < 6; r++) p[6 * j + r] = v[r];
  }
  const float* iprow = ipose + (size_t)row * 144;
  float* orow = out + (size_t)row * 157 + 3;
  #pragma unroll
  for (int t = 0; t < 144; t++) orow[t] = p[t] + iprow[t];
}

// ---------------------------------------------------------------------------
extern "C" void kernel_launch(void* const* d_in, const int* in_sizes, int n_in,
                              void* d_out, int out_size, void* d_ws, size_t ws_size,
                              hipStream_t stream) {
  const float* x      = (const float*)d_in[0];
  const float* ipose  = (const float*)d_in[1];
  const float* ishape = (const float*)d_in[2];
  const float* icam   = (const float*)d_in[3];
  const float* fc1w   = (const float*)d_in[4];
  const float* fc1b   = (const float*)d_in[5];
  const float* fc2w   = (const float*)d_in[6];
  const float* fc2b   = (const float*)d_in[7];
  const float* dsw    = (const float*)d_in[8];
  const float* dsb    = (const float*)d_in[9];
  const float* dcw    = (const float*)d_in[10];
  const float* dcb    = (const float*)d_in[11];
  const float* ktd    = (const float*)d_in[12];
  const float* ktdb   = (const float*)d_in[13];
  int rows = in_sizes[0] / 256;
  float* ws = (float*)d_ws;

  float* Gp = ws;                                     // 4 * 59200 = 236800 f
  float* Hp = ws + 236800;                            // 4 * 3520  = 14080 f -> 250880
  float* Cb = ws + 250880;                            // 160 f -> 251040
  unsigned short* Mb = (unsigned short*)(ws + 251040); // byte 1004160 (16-aligned), 33920 f
  float* pb = nullptr;
  size_t need = (size_t)284960 * 4 + (size_t)rows * 144 * 4;
  if (ws_size >= need) pb = ws + 284960;              // packed pose-base [rows][144]

  combine_part<<<dim3(7, 41, 4), 256, 0, stream>>>(ktd, dcw, dsw, fc2w, fc2b,
                                                   fc1w, fc1b, Gp, Hp);
  assembleM<<<160, 256, 0, stream>>>(Gp, Hp, dcw, dcb, dsb, ktd, ktdb, Mb, Cb);
  main_gemm<<<rows / 64, 256, 0, stream>>>(x, ipose, ishape, icam, Mb, Cb,
                                           (float*)d_out, pb, rows);
  fixup<<<rows / 256, 256, 0, stream>>>(ktd, ipose,
                                        pb ? pb : (float*)d_out,
                                        pb ? 144 : 157, pb ? 0 : 3,
                                        (float*)d_out, rows);
}